// Round 7
// baseline (94.533 us; speedup 1.0000x reference)
//
#include <hip/hip_runtime.h>

// Problem constants (match reference.py)
#define NB 65536   // trajectories
#define NT 512     // time points (NT-1 steps)
#define TPB 128    // trajectories per block: 4 waves x 32 active lanes

typedef float f32x2 __attribute__((ext_vector_type(2)));

static __device__ __forceinline__ f32x2 fma2(f32x2 a, f32x2 b, f32x2 c) {
    return __builtin_elementwise_fma(a, b, c);
}

// Occupancy doubling under a fixed trajectory budget: 2048 waves with 32
// active lanes each (lanes 32-63 masked off) -> 2 waves/SIMD. Each SIMD now
// interleaves two independent RK4 chains, hiding per-wave in-order stalls.
// State packed as f32x2 (b,s) -> v_pk_fma_f32 for stage-input/k/update ops.
__global__ __launch_bounds__(256) void rk4_biosystem_kernel(
    const float* __restrict__ y0,
    const float* __restrict__ t_eval,
    const float* __restrict__ D_seq,
    const float* __restrict__ K_m_p,
    const float* __restrict__ s_e_p,
    const float* __restrict__ mu_max_p,
    float* __restrict__ out)
{
    __shared__ float s_dt[NT - 1];
    __shared__ float s_D[NT - 1];

    const int tid = threadIdx.x;
    for (int i = tid; i < NT - 1; i += 256) {
        s_dt[i] = t_eval[i + 1] - t_eval[i];   // dt exactly as reference
        s_D[i]  = D_seq[i];
    }
    __syncthreads();

    // Half-wave: keep lanes 0-31 of each wave, retire lanes 32-63.
    if ((tid & 63) >= 32) return;

    const float K_m    = K_m_p[0];
    const float s_e    = s_e_p[0];
    const float mu_max = mu_max_p[0];

    const int traj = blockIdx.x * TPB + (tid >> 6) * 32 + (tid & 31);

    const f32x2* __restrict__ y0v = (const f32x2*)y0;
    f32x2 y = y0v[traj];                      // (b, s)

    f32x2* __restrict__ out2 = (f32x2*)out;   // out[t][traj][2] as vec2
    out2[traj] = y;                           // row 0 = y0
    f32x2* __restrict__ op = out2 + traj;     // walking output pointer

    // Distance-2 software pipeline for per-step uniforms.
    float dt0 = s_dt[0], D0 = s_D[0];
    float dt1 = s_dt[1], D1 = s_D[1];

    #pragma unroll 8
    for (int t = 0; t < NT - 1; ++t) {
        const float dt = dt0;
        const float D  = D0;
        dt0 = dt1; D0 = D1;
        const int tn = (t < NT - 3) ? (t + 2) : (NT - 2);
        dt1 = s_dt[tn];
        D1  = s_D[tn];

        // rhs(y): rho*b = mu_max*s*b * rcp(K_m+s);
        //         k = ( rb - D*b,  D*(s_e-s) - rb )  as one packed fma
        auto rhs = [&](f32x2 yi) -> f32x2 {
            const float bi = yi.x, si = yi.y;
            const float inv = __builtin_amdgcn_rcpf(K_m + si);
            const float num = (mu_max * si) * bi;
            const float rb  = num * inv;
            f32x2 coef; coef.x = -D;  coef.y = D;
            f32x2 vec;  vec.x  = bi;  vec.y  = s_e - si;
            f32x2 addn; addn.x = rb;  addn.y = -rb;
            return fma2(coef, vec, addn);
        };

        const float h2 = dt * 0.5f;
        f32x2 h2v; h2v.x = h2; h2v.y = h2;
        f32x2 dtv; dtv.x = dt; dtv.y = dt;

        const f32x2 k1 = rhs(y);
        const f32x2 k2 = rhs(fma2(h2v, k1, y));
        const f32x2 k3 = rhs(fma2(h2v, k2, y));
        const f32x2 k4 = rhs(fma2(dtv, k3, y));

        const f32x2 t14 = k1 + k4;
        const f32x2 t23 = k2 + k3;
        f32x2 twov; twov.x = 2.0f; twov.y = 2.0f;
        const f32x2 ksum = fma2(twov, t23, t14);

        const float h6 = dt * (1.0f / 6.0f);
        f32x2 h6v; h6v.x = h6; h6v.y = h6;
        y = fma2(h6v, ksum, y);

        op += NB;
        *op = y;
    }
}

extern "C" void kernel_launch(void* const* d_in, const int* in_sizes, int n_in,
                              void* d_out, int out_size, void* d_ws, size_t ws_size,
                              hipStream_t stream) {
    const float* y0     = (const float*)d_in[0];
    const float* t_eval = (const float*)d_in[1];
    const float* D_seq  = (const float*)d_in[2];
    const float* K_m    = (const float*)d_in[3];
    const float* s_e    = (const float*)d_in[4];
    const float* mu_max = (const float*)d_in[5];
    float* out = (float*)d_out;

    dim3 grid(NB / TPB);   // 512 blocks -> 2048 half-waves -> 2 waves/SIMD
    dim3 block(256);
    rk4_biosystem_kernel<<<grid, block, 0, stream>>>(y0, t_eval, D_seq, K_m, s_e, mu_max, out);
}

// Round 8
// 93.616 us; speedup vs baseline: 1.0098x; 1.0098x over previous
//
#include <hip/hip_runtime.h>

// Problem constants (match reference.py)
#define NB 65536   // trajectories
#define NT 512     // time points (NT-1 steps)

typedef float f32x2 __attribute__((ext_vector_type(2)));
typedef float f32x4 __attribute__((ext_vector_type(4)));

// Prepass: u[t] = {h2, h6, D, dt} per step, into d_ws. Main kernel reads these
// at uniform addresses -> s_load_dwordx4 (scalar pipe, zero VALU issue).
__global__ void prep_uniforms_kernel(const float* __restrict__ t_eval,
                                     const float* __restrict__ D_seq,
                                     f32x4* __restrict__ u)
{
    const int i = blockIdx.x * 256 + threadIdx.x;
    if (i >= NT) return;
    f32x4 v;
    if (i < NT - 1) {
        const float dt = t_eval[i + 1] - t_eval[i];   // exactly as reference
        v.x = dt * 0.5f;
        v.y = dt * (1.0f / 6.0f);
        v.z = D_seq[i];
        v.w = dt;
    } else {
        v.x = 0.0f; v.y = 0.0f; v.z = 0.0f; v.w = 0.0f;
    }
    u[i] = v;
}

// 1 trajectory per thread: 65536 threads = 1024 waves = 1 wave/SIMD.
// All per-step uniforms come from SGPRs (scalar loads of d_ws); stores use a
// uniform row pointer (SGPR base) + fixed 32-bit lane offset (saddr form).
__global__ __launch_bounds__(256) void rk4_biosystem_kernel(
    const float* __restrict__ y0,
    const f32x4* __restrict__ u,
    const float* __restrict__ K_m_p,
    const float* __restrict__ s_e_p,
    const float* __restrict__ mu_max_p,
    float* __restrict__ out)
{
    const float K_m    = K_m_p[0];
    const float s_e    = s_e_p[0];
    const float mu_max = mu_max_p[0];

    const int traj = blockIdx.x * 256 + threadIdx.x;

    const f32x2* __restrict__ y0v = (const f32x2*)y0;
    f32x2 y = y0v[traj];                    // (b, s)
    float b = y.x, s = y.y;

    f32x2* __restrict__ out2 = (f32x2*)out; // out[t][traj][2] as vec2
    out2[traj] = y;                         // row 0 = y0

    // Distance-2 rotation of per-step uniforms (lands in SGPRs).
    f32x4 u0 = u[0];
    f32x4 u1 = u[1];

    // rhs: rb = mu_max*s*b * rcp(K_m+s); db = rb - D*b; ds = D*(s_e-s) - rb
    #define RHS(bb, ss, db, ds)                                  \
        {                                                        \
            float inv = __builtin_amdgcn_rcpf(K_m + (ss));       \
            float num = (mu_max * (ss)) * (bb);                  \
            float rb  = num * inv;                               \
            db = __builtin_fmaf(-D, (bb), rb);                   \
            ds = __builtin_fmaf(D, s_e - (ss), -rb);             \
        }

    #pragma unroll 8
    for (int t = 0; t < NT - 1; ++t) {
        const float h2 = u0.x;
        const float h6 = u0.y;
        const float D  = u0.z;
        const float dt = u0.w;
        // rotate pipeline; fetch step t+2's uniforms (clamped)
        u0 = u1;
        u1 = u[(t < NT - 3) ? (t + 2) : (NT - 2)];

        float k1b, k1s, k2b, k2s, k3b, k3s, k4b, k4s;
        RHS(b, s, k1b, k1s);
        RHS(__builtin_fmaf(h2, k1b, b), __builtin_fmaf(h2, k1s, s), k2b, k2s);
        RHS(__builtin_fmaf(h2, k2b, b), __builtin_fmaf(h2, k2s, s), k3b, k3s);
        RHS(__builtin_fmaf(dt, k3b, b), __builtin_fmaf(dt, k3s, s), k4b, k4s);

        // parallel reduction trees for the k-sums
        const float sb  = (k1b + k4b) + 2.0f * (k2b + k3b);
        const float ss_ = (k1s + k4s) + 2.0f * (k2s + k3s);
        b = __builtin_fmaf(h6, sb, b);
        s = __builtin_fmaf(h6, ss_, s);

        // uniform row pointer (SGPR) + fixed lane offset -> saddr store
        f32x2* __restrict__ row = out2 + (size_t)(t + 1) * NB;
        f32x2 v; v.x = b; v.y = s;
        row[traj] = v;
    }
    #undef RHS
}

extern "C" void kernel_launch(void* const* d_in, const int* in_sizes, int n_in,
                              void* d_out, int out_size, void* d_ws, size_t ws_size,
                              hipStream_t stream) {
    const float* y0     = (const float*)d_in[0];
    const float* t_eval = (const float*)d_in[1];
    const float* D_seq  = (const float*)d_in[2];
    const float* K_m    = (const float*)d_in[3];
    const float* s_e    = (const float*)d_in[4];
    const float* mu_max = (const float*)d_in[5];
    float* out = (float*)d_out;
    f32x4* u = (f32x4*)d_ws;   // 512 * 16 B = 8 KiB of scratch

    prep_uniforms_kernel<<<dim3(2), dim3(256), 0, stream>>>(t_eval, D_seq, u);
    rk4_biosystem_kernel<<<dim3(NB / 256), dim3(256), 0, stream>>>(
        y0, u, K_m, s_e, mu_max, out);
}

// Round 9
// 62.588 us; speedup vs baseline: 1.5104x; 1.4958x over previous
//
#include <hip/hip_runtime.h>

// Problem constants (match reference.py)
#define NB 65536   // trajectories
#define NT 512     // time points (NT-1 steps)

typedef float f32x2 __attribute__((ext_vector_type(2)));
typedef float f32x4 __attribute__((ext_vector_type(4)));

// 1 trajectory per thread: 65536 threads = 1024 waves = 1 wave/SIMD.
// Uniforms stay on the lgkm path (LDS) -- R8 proved in-loop VMEM uniform
// loads serialize against the store stream via in-order vmcnt.
// Per-step uniforms packed {h2,h6,D,dt} -> one ds_read_b128, imm offsets,
// no clamp/rotation. den_i = fma(h, k_is, K_m+s) removes the serial add
// before each rcp (chain -16 cyc/step).
__global__ __launch_bounds__(256) void rk4_biosystem_kernel(
    const float* __restrict__ y0,
    const float* __restrict__ t_eval,
    const float* __restrict__ D_seq,
    const float* __restrict__ K_m_p,
    const float* __restrict__ s_e_p,
    const float* __restrict__ mu_max_p,
    float* __restrict__ out)
{
    __shared__ f32x4 u4[NT];   // {h2, h6, D, dt} per step; 8 KiB

    const int tid = threadIdx.x;
    for (int i = tid; i < NT; i += 256) {
        const int j = (i < NT - 1) ? i : (NT - 2);   // pad tail (never used)
        const float dt = t_eval[j + 1] - t_eval[j];  // dt exactly as reference
        f32x4 v;
        v.x = dt * 0.5f;
        v.y = dt * (1.0f / 6.0f);
        v.z = D_seq[j];
        v.w = dt;
        u4[i] = v;
    }
    __syncthreads();

    const float K_m    = K_m_p[0];
    const float s_e    = s_e_p[0];
    const float mu_max = mu_max_p[0];

    const int traj = blockIdx.x * 256 + tid;

    const f32x2* __restrict__ y0v = (const f32x2*)y0;
    f32x2 y = y0v[traj];                    // (b, s)
    float b = y.x, s = y.y;

    f32x2* __restrict__ out2 = (f32x2*)out; // out[t][traj][2] as vec2
    out2[traj] = y;                         // row 0 = y0
    f32x2* __restrict__ op = out2 + traj;   // walking output pointer

    #pragma unroll 8
    for (int t = 0; t < NT - 1; ++t) {
        const f32x4 u = u4[t];
        const float h2 = u.x, h6 = u.y, D = u.z, dt = u.w;

        // once per step, off the stage chain
        const float sK  = K_m + s;          // K_m + s
        const float ses = s_e - s;          // s_e - s
        const float ms  = mu_max * s;

        // stage 1 (ss = s, bb = b)
        const float inv1 = __builtin_amdgcn_rcpf(sK);
        const float num1 = ms * b;
        const float rb1  = num1 * inv1;
        const float k1b  = __builtin_fmaf(-D, b, rb1);
        const float k1s  = __builtin_fmaf(D, ses, -rb1);

        // stage 2
        const float den2 = __builtin_fmaf(h2, k1s, sK);   // K_m + (s + h2*k1s)
        const float inv2 = __builtin_amdgcn_rcpf(den2);
        const float bb2  = __builtin_fmaf(h2, k1b, b);
        const float ss2  = __builtin_fmaf(h2, k1s, s);
        const float num2 = (mu_max * ss2) * bb2;
        const float rb2  = num2 * inv2;
        const float k2b  = __builtin_fmaf(-D, bb2, rb2);
        const float k2s  = __builtin_fmaf(D, s_e - ss2, -rb2);

        // stage 3
        const float den3 = __builtin_fmaf(h2, k2s, sK);
        const float inv3 = __builtin_amdgcn_rcpf(den3);
        const float bb3  = __builtin_fmaf(h2, k2b, b);
        const float ss3  = __builtin_fmaf(h2, k2s, s);
        const float num3 = (mu_max * ss3) * bb3;
        const float rb3  = num3 * inv3;
        const float k3b  = __builtin_fmaf(-D, bb3, rb3);
        const float k3s  = __builtin_fmaf(D, s_e - ss3, -rb3);

        // stage 4 (full dt)
        const float den4 = __builtin_fmaf(dt, k3s, sK);
        const float inv4 = __builtin_amdgcn_rcpf(den4);
        const float bb4  = __builtin_fmaf(dt, k3b, b);
        const float ss4  = __builtin_fmaf(dt, k3s, s);
        const float num4 = (mu_max * ss4) * bb4;
        const float rb4  = num4 * inv4;
        const float k4b  = __builtin_fmaf(-D, bb4, rb4);
        const float k4s  = __builtin_fmaf(D, s_e - ss4, -rb4);

        // parallel reduction trees + update
        const float sb  = (k1b + k4b) + 2.0f * (k2b + k3b);
        const float ss_ = (k1s + k4s) + 2.0f * (k2s + k3s);
        b = __builtin_fmaf(h6, sb, b);
        s = __builtin_fmaf(h6, ss_, s);

        op += NB;
        f32x2 v; v.x = b; v.y = s;
        *op = v;
    }
}

extern "C" void kernel_launch(void* const* d_in, const int* in_sizes, int n_in,
                              void* d_out, int out_size, void* d_ws, size_t ws_size,
                              hipStream_t stream) {
    const float* y0     = (const float*)d_in[0];
    const float* t_eval = (const float*)d_in[1];
    const float* D_seq  = (const float*)d_in[2];
    const float* K_m    = (const float*)d_in[3];
    const float* s_e    = (const float*)d_in[4];
    const float* mu_max = (const float*)d_in[5];
    float* out = (float*)d_out;

    dim3 grid(NB / 256);
    dim3 block(256);
    rk4_biosystem_kernel<<<grid, block, 0, stream>>>(y0, t_eval, D_seq, K_m, s_e, mu_max, out);
}